// Round 8
// baseline (420.522 us; speedup 1.0000x reference)
//
#include <hip/hip_runtime.h>
#include <stdint.h>

// HeteroSTHN edge-predictor, fused bf16-MFMA, B direct global->VGPR (no LDS B path).
// pred[p,t] = out_W[t] . relu(h_src.src_W[t] + src_b[t] + h_dst.dst_W[t] + dst_b[t]) + out_b[t]
// out[p] = any(mask[p]) ? max_t(masked pred) : 0
//
// Round-6 post-mortem: LDS-port-bound (4x per-wave B-read redundancy through one LDS port,
// 12.4M bank-conflict cycles). Fix: prep kernel stores B fragment-major (1024 B record per
// (t,ksg,nt) = exact 64-lane MFMA B fragment); main kernel loads B straight to VGPRs with
// coalesced dwordx4, double-buffered. All 8 waves read identical addresses in lockstep ->
// L1 (32 KB) serves the redundancy. LDS holds only mask/bias/outW (~15 KB). No B staging,
// no barriers in the K loop (one __syncthreads per t to keep waves L1-coherent).

typedef float f32x4 __attribute__((ext_vector_type(4)));
typedef short s16x8 __attribute__((ext_vector_type(8)));

static constexpr int E_NODES = 65536;
static constexpr int D_DIM   = 200;
static constexpr int H_DIM   = 100;
static constexpr int T_TYPES = 8;
static constexpr int NPAD    = 112;   // padded H (7 x 16)
static constexpr int NT      = 7;
static constexpr int KS      = 13;    // K sub-slabs of 32 (merged K: src<200, dst 200..399, pad to 416)
static constexpr int P_TILE  = 256;
static constexpr int THREADS = 512;   // 8 waves, each owns 32 rows
static constexpr int REC_B   = 1024;              // bytes per (t,ksg,nt) fragment record
static constexpr int KSG_B   = NT * REC_B;        // 7168
static constexpr int T_B     = KS * KSG_B;        // 93184
static constexpr int WT_ELEMS = T_TYPES * KS * NT * 512;  // 372736 bf16 = 728 KB

__device__ unsigned short g_Wt[WT_ELEMS];   // fragment-major bf16 B image

__device__ __forceinline__ unsigned short f2bf(float f) {
  unsigned int u = __float_as_uint(f);
  u += 0x7FFFu + ((u >> 16) & 1u);   // round-to-nearest-even
  return (unsigned short)(u >> 16);
}

__global__ void prep_weights(const float* __restrict__ srcW, const float* __restrict__ dstW) {
  int idx = blockIdx.x * blockDim.x + threadIdx.x;
  if (idx >= WT_ELEMS) return;
  // element = record(rec)*512 + lane*8 + e ; rec = (t*13 + ksg)*7 + nt
  int e   = idx & 7;
  int l   = (idx >> 3) & 63;
  int rec = idx >> 9;
  int nt  = rec % 7;
  int r2  = rec / 7;
  int ksg = r2 % 13;
  int t   = r2 / 13;
  int j   = nt * 16 + (l & 15);            // B col (H dim)
  int k   = ksg * 32 + ((l >> 4) << 3) + e; // merged K
  float v = 0.0f;
  if (j < H_DIM) {
    if (k < D_DIM)          v = srcW[(t * D_DIM + k) * H_DIM + j];
    else if (k < 2 * D_DIM) v = dstW[(t * D_DIM + (k - D_DIM)) * H_DIM + j];
  }
  g_Wt[idx] = f2bf(v);
}

__global__ __launch_bounds__(THREADS, 2)
void fused_pred(const float* __restrict__ h,
                const float* __restrict__ srcB, const float* __restrict__ dstB,
                const float* __restrict__ outW, const float* __restrict__ outB,
                const int* __restrict__ poss, float* __restrict__ out) {
  __shared__ __align__(16) int ldsMask[P_TILE * T_TYPES];   // 8 KB
  __shared__ float ldsBias[T_TYPES * NPAD];                 // 3.5 KB
  __shared__ float ldsOutw[T_TYPES * NPAD];                 // 3.5 KB
  __shared__ float ldsOutb[T_TYPES];

  const int tid  = threadIdx.x;
  const int lane = tid & 63;
  const int w    = tid >> 6;       // wave 0..7, owns rows [32w, 32w+32)
  const int c    = lane & 15;
  const int g    = lane >> 4;

  // XCD-paired remap: pos/neg tiles over the same src rows land adjacent per-XCD.
  const int l     = ((int)blockIdx.x & 7) * 64 + ((int)blockIdx.x >> 3);
  const int which = l & 1;
  const int grp   = l >> 1;
  const int P0    = which * E_NODES + grp * P_TILE;

  // constants + mask -> LDS (read-only after the prologue barrier)
#pragma unroll
  for (int i = 0; i < 2; ++i) {
    int idx = i * THREADS + tid;
    if (idx < T_TYPES * NPAD) {
      int t = idx / NPAD, j = idx - t * NPAD;
      float bb = 0.f, ww = 0.f;
      if (j < H_DIM) {
        bb = srcB[t * H_DIM + j] + dstB[t * H_DIM + j];
        ww = outW[t * H_DIM + j];
      }
      ldsBias[idx] = bb;
      ldsOutw[idx] = ww;
    }
  }
  if (tid < T_TYPES) ldsOutb[tid] = outB[tid];
  ((int4*)ldsMask)[tid] = ((const int4*)(poss + (size_t)P0 * T_TYPES))[tid];

  // A fragments in registers: A[mt][ks], merged K, k = ks*32 + g*8 + e
  s16x8 A[2][KS];
#pragma unroll
  for (int mt = 0; mt < 2; ++mt) {
    const int row = w * 32 + mt * 16 + c;
    const int p   = P0 + row;
    const float* sp = h + (size_t)(p & (E_NODES - 1)) * D_DIM;
    const float* dp = h + ((size_t)E_NODES + (size_t)p) * D_DIM;
#pragma unroll
    for (int ks = 0; ks < KS; ++ks) {
      const int k0 = ks * 32 + g * 8;
      s16x8 a = {};
      if (k0 < 2 * D_DIM) {                 // only ks=12, g>=2 is pad
        const float* base = (k0 < D_DIM) ? (sp + k0) : (dp + (k0 - D_DIM));
        float4 f0 = *(const float4*)(base);
        float4 f1 = *(const float4*)(base + 4);
        a[0] = (short)f2bf(f0.x); a[1] = (short)f2bf(f0.y);
        a[2] = (short)f2bf(f0.z); a[3] = (short)f2bf(f0.w);
        a[4] = (short)f2bf(f1.x); a[5] = (short)f2bf(f1.y);
        a[6] = (short)f2bf(f1.z); a[7] = (short)f2bf(f1.w);
      }
      A[mt][ks] = a;
    }
  }

  const f32x4 ZERO4 = {0.f, 0.f, 0.f, 0.f};
  f32x4 acc[2][NT];
  float runmax[2][4];
#pragma unroll
  for (int mt = 0; mt < 2; ++mt) {
#pragma unroll
    for (int nt = 0; nt < NT; ++nt) acc[mt][nt] = ZERO4;
#pragma unroll
    for (int r = 0; r < 4; ++r) runmax[mt][r] = -1e30f;
  }

  __syncthreads();   // constants/mask visible

  for (int t = 0; t < T_TYPES; ++t) {
    // per-lane fragment base for this t (lane offset baked in; nt/ksg via immediates)
    const char* bt = (const char*)g_Wt + (size_t)t * T_B + lane * 16;

    s16x8 bb[2][NT];   // double-buffered B fragments; all indices compile-time
#pragma unroll
    for (int nt = 0; nt < NT; ++nt)
      bb[0][nt] = *(const s16x8*)(bt + 0 * KSG_B + nt * REC_B);

#pragma unroll
    for (int ksg = 0; ksg < KS; ++ksg) {
      const int cur = ksg & 1;
      if (ksg < KS - 1) {
#pragma unroll
        for (int nt = 0; nt < NT; ++nt)
          bb[cur ^ 1][nt] = *(const s16x8*)(bt + (ksg + 1) * KSG_B + nt * REC_B);
      }
      const s16x8 a0 = A[0][ksg];
      const s16x8 a1 = A[1][ksg];
#pragma unroll
      for (int nt = 0; nt < NT; ++nt) {
        acc[0][nt] = __builtin_amdgcn_mfma_f32_16x16x32_bf16(a0, bb[cur][nt], acc[0][nt], 0, 0, 0);
        acc[1][nt] = __builtin_amdgcn_mfma_f32_16x16x32_bf16(a1, bb[cur][nt], acc[1][nt], 0, 0, 0);
      }
    }

    // epilogue for t: bias + relu + outW dot, 16-lane reduce, masked running max
    {
      float bj[NT], wj[NT];
#pragma unroll
      for (int nt = 0; nt < NT; ++nt) {
        bj[nt] = ldsBias[t * NPAD + nt * 16 + c];
        wj[nt] = ldsOutw[t * NPAD + nt * 16 + c];
      }
      const float ob = ldsOutb[t];
#pragma unroll
      for (int mt = 0; mt < 2; ++mt) {
#pragma unroll
        for (int r = 0; r < 4; ++r) {
          float v = 0.f;
#pragma unroll
          for (int nt = 0; nt < NT; ++nt)
            v += fmaxf(acc[mt][nt][r] + bj[nt], 0.f) * wj[nt];
          v += __shfl_xor(v, 1);
          v += __shfl_xor(v, 2);
          v += __shfl_xor(v, 4);
          v += __shfl_xor(v, 8);
          const float pred = v + ob;
          const int row = w * 32 + mt * 16 + g * 4 + r;   // C/D: row=(lane>>4)*4+reg, col=lane&15
          if (ldsMask[row * T_TYPES + t] != 0)
            runmax[mt][r] = fmaxf(runmax[mt][r], pred);
        }
#pragma unroll
        for (int nt = 0; nt < NT; ++nt) acc[mt][nt] = ZERO4;
      }
    }

    __syncthreads();   // keep the 8 waves in step so L1 serves the shared B records
  }

  if (c == 0) {
#pragma unroll
    for (int mt = 0; mt < 2; ++mt)
#pragma unroll
      for (int r = 0; r < 4; ++r) {
        const int row = w * 32 + mt * 16 + g * 4 + r;
        const float v = runmax[mt][r];
        out[P0 + row] = (v > -1e29f) ? v : 0.0f;   // where(any_valid, best, 0)
      }
  }
}

extern "C" void kernel_launch(void* const* d_in, const int* in_sizes, int n_in,
                              void* d_out, int out_size, void* d_ws, size_t ws_size,
                              hipStream_t stream) {
  const float* h    = (const float*)d_in[0];
  const float* srcW = (const float*)d_in[1];
  const float* srcB = (const float*)d_in[2];
  const float* dstW = (const float*)d_in[3];
  const float* dstB = (const float*)d_in[4];
  const float* outW = (const float*)d_in[5];
  const float* outB = (const float*)d_in[6];
  const int*   poss = (const int*)d_in[7];
  float* out = (float*)d_out;

  prep_weights<<<(WT_ELEMS + 255) / 256, 256, 0, stream>>>(srcW, dstW);

  const int nblocks = (2 * E_NODES) / P_TILE;   // 512
  fused_pred<<<nblocks, THREADS, 0, stream>>>(h, srcB, dstB, outW, outB, poss, out);
}

// Round 9
// 418.486 us; speedup vs baseline: 1.0049x; 1.0049x over previous
//
#include <hip/hip_runtime.h>
#include <stdint.h>

// HeteroSTHN edge-predictor, fused bf16-MFMA.
// Round-8 post-mortem: direct global->VGPR B = latency-bound (MfmaUtil 15%). Round-6
// post-mortem (corrected): row-major LDS B slab = 8-way bank conflict on every ds_read_b128
// (row stride 256 B puts all 16 c-lanes on the same bank set; XOR only spread 8 slots).
// This version:
//  * B in LDS, FRAGMENT-MAJOR: 1024 B record per (ksg,nt) = one wave's MFMA B-fragment.
//    ds_read_b128 at rec*1024 + lane*16 is a contiguous 1024 B wave read: conflict-free
//    by construction. global_load_lds staging is a pure linear copy (no swizzle).
//  * 64 rows/wave (4 A-frags, P_TILE=256, 4 waves): halves LDS-read bytes per FLOP vs
//    32 rows/wave (B-traffic/FLOP = 1/M_wave). ~410 regs -> __launch_bounds__(256,1).
//  * Half-t slabs (ksg 0-6, 7-12), issue-early stage + one __syncthreads per interval
//    (race-free round-6 sync structure; no raw-barrier/vmcnt fragility).

typedef float f32x4 __attribute__((ext_vector_type(4)));
typedef short s16x8 __attribute__((ext_vector_type(8)));

static constexpr int E_NODES = 65536;
static constexpr int D_DIM   = 200;
static constexpr int H_DIM   = 100;
static constexpr int T_TYPES = 8;
static constexpr int NPAD    = 112;   // padded H (7 x 16)
static constexpr int NT      = 7;
static constexpr int KS      = 13;    // K sub-slabs of 32 (merged K: src<200, dst 200..399, pad 416)
static constexpr int P_TILE  = 256;
static constexpr int THREADS = 256;   // 4 waves x 64 rows
static constexpr int REC_B   = 1024;               // bytes per (ksg,nt) fragment record
static constexpr int KSG_B   = NT * REC_B;         // 7168 B per ksg group
static constexpr int T_B     = KS * KSG_B;         // 93184 B per t
static constexpr int WT_ELEMS = T_TYPES * KS * NT * 512;  // 372736 bf16 = 728 KB
static constexpr int SLAB0_REC = 7 * NT;           // ksg 0..6  : 49 recs = 50176 B
static constexpr int SLAB1_REC = 6 * NT;           // ksg 7..12 : 42 recs = 43008 B

__device__ unsigned short g_Wt[WT_ELEMS];   // fragment-major bf16 B image

__device__ __forceinline__ unsigned short f2bf(float f) {
  unsigned int u = __float_as_uint(f);
  u += 0x7FFFu + ((u >> 16) & 1u);   // round-to-nearest-even
  return (unsigned short)(u >> 16);
}

__global__ void prep_weights(const float* __restrict__ srcW, const float* __restrict__ dstW) {
  int idx = blockIdx.x * blockDim.x + threadIdx.x;
  if (idx >= WT_ELEMS) return;
  // element = rec*512 + lane*8 + e ; rec = (t*13 + ksg)*7 + nt
  int e   = idx & 7;
  int l   = (idx >> 3) & 63;
  int rec = idx >> 9;
  int nt  = rec % 7;
  int r2  = rec / 7;
  int ksg = r2 % 13;
  int t   = r2 / 13;
  int j   = nt * 16 + (l & 15);             // B col (H dim)
  int k   = ksg * 32 + ((l >> 4) << 3) + e; // merged K
  float v = 0.0f;
  if (j < H_DIM) {
    if (k < D_DIM)          v = srcW[(t * D_DIM + k) * H_DIM + j];
    else if (k < 2 * D_DIM) v = dstW[(t * D_DIM + (k - D_DIM)) * H_DIM + j];
  }
  g_Wt[idx] = f2bf(v);
}

template <int NREC>
__device__ __forceinline__ void stage(const char* src, unsigned short* dst, int tid) {
  char* d = (char*)dst;
  constexpr int XF = NREC * 64;   // 16 B transfers
#pragma unroll
  for (int i = 0; i < (XF + THREADS - 1) / THREADS; ++i) {
    const int idx = i * THREADS + tid;
    if (idx < XF) {
      __builtin_amdgcn_global_load_lds(
          (const __attribute__((address_space(1))) void*)(src + idx * 16),
          (__attribute__((address_space(3))) void*)(d + idx * 16),
          16, 0, 0);
    }
  }
}

__global__ __launch_bounds__(THREADS, 1)
void fused_pred(const float* __restrict__ h,
                const float* __restrict__ srcB, const float* __restrict__ dstB,
                const float* __restrict__ outW, const float* __restrict__ outB,
                const int* __restrict__ poss, float* __restrict__ out) {
  __shared__ __align__(16) unsigned short ldsB[2][SLAB0_REC * 512];  // 2 x 50176 B
  __shared__ __align__(16) int ldsMask[P_TILE * T_TYPES];            // 8 KB
  __shared__ float ldsBias[T_TYPES * NPAD];                          // 3.5 KB
  __shared__ float ldsOutw[T_TYPES * NPAD];                          // 3.5 KB
  __shared__ float ldsOutb[T_TYPES];

  const int tid  = threadIdx.x;
  const int lane = tid & 63;
  const int w    = tid >> 6;       // wave 0..3, owns rows [64w, 64w+64)
  const int c    = lane & 15;
  const int g    = lane >> 4;

  // XCD-paired remap: pos/neg tiles over the same src rows adjacent per-XCD.
  const int l     = ((int)blockIdx.x & 7) * 64 + ((int)blockIdx.x >> 3);
  const int which = l & 1;
  const int grp   = l >> 1;
  const int P0    = which * E_NODES + grp * P_TILE;

  // first slab in flight under the whole prologue
  stage<SLAB0_REC>((const char*)g_Wt, ldsB[0], tid);
  __builtin_amdgcn_sched_barrier(0);

  // constants + mask -> LDS
#pragma unroll
  for (int i = 0; i < 4; ++i) {
    int idx = i * THREADS + tid;
    if (idx < T_TYPES * NPAD) {
      int t = idx / NPAD, j = idx - t * NPAD;
      float bb = 0.f, ww = 0.f;
      if (j < H_DIM) {
        bb = srcB[t * H_DIM + j] + dstB[t * H_DIM + j];
        ww = outW[t * H_DIM + j];
      }
      ldsBias[idx] = bb;
      ldsOutw[idx] = ww;
    }
  }
  if (tid < T_TYPES) ldsOutb[tid] = outB[tid];
  ((int4*)ldsMask)[tid]           = ((const int4*)(poss + (size_t)P0 * T_TYPES))[tid];
  ((int4*)ldsMask)[tid + THREADS] = ((const int4*)(poss + (size_t)P0 * T_TYPES))[tid + THREADS];

  // A fragments in registers: A[mt][ks], merged K, k = ks*32 + g*8 + e; 64 rows/wave
  s16x8 A[4][KS];
#pragma unroll
  for (int mt = 0; mt < 4; ++mt) {
    const int row = w * 64 + mt * 16 + c;
    const int p   = P0 + row;
    const float* sp = h + (size_t)(p & (E_NODES - 1)) * D_DIM;
    const float* dp = h + ((size_t)E_NODES + (size_t)p) * D_DIM;
#pragma unroll
    for (int ks = 0; ks < KS; ++ks) {
      const int k0 = ks * 32 + g * 8;
      s16x8 a = {};
      if (k0 < 2 * D_DIM) {                 // only ks=12, g>=2 is pad
        const float* base = (k0 < D_DIM) ? (sp + k0) : (dp + (k0 - D_DIM));
        float4 f0 = *(const float4*)(base);
        float4 f1 = *(const float4*)(base + 4);
        a[0] = (short)f2bf(f0.x); a[1] = (short)f2bf(f0.y);
        a[2] = (short)f2bf(f0.z); a[3] = (short)f2bf(f0.w);
        a[4] = (short)f2bf(f1.x); a[5] = (short)f2bf(f1.y);
        a[6] = (short)f2bf(f1.z); a[7] = (short)f2bf(f1.w);
      }
      A[mt][ks] = a;
    }
  }

  const f32x4 ZERO4 = {0.f, 0.f, 0.f, 0.f};
  f32x4 acc[4][NT];
  float runmax[4][4];
#pragma unroll
  for (int mt = 0; mt < 4; ++mt) {
#pragma unroll
    for (int nt = 0; nt < NT; ++nt) acc[mt][nt] = ZERO4;
#pragma unroll
    for (int r = 0; r < 4; ++r) runmax[mt][r] = -1e30f;
  }

  __syncthreads();   // slab 0 staged, constants/mask visible

  int buf = 0;
  for (int t = 0; t < T_TYPES; ++t) {
    // ---- interval (t, sl=0): ksg 0..6 ----
    {
      stage<SLAB1_REC>((const char*)g_Wt + (size_t)t * T_B + 7 * KSG_B, ldsB[buf ^ 1], tid);
      __builtin_amdgcn_sched_barrier(0);
      const char* B = (const char*)ldsB[buf];
#pragma unroll
      for (int kk = 0; kk < 7; ++kk) {
        s16x8 b[NT];
#pragma unroll
        for (int nt = 0; nt < NT; ++nt)
          b[nt] = *(const s16x8*)(B + (kk * 7 + nt) * REC_B + lane * 16);
#pragma unroll
        for (int nt = 0; nt < NT; ++nt) {
#pragma unroll
          for (int mt = 0; mt < 4; ++mt)
            acc[mt][nt] = __builtin_amdgcn_mfma_f32_16x16x32_bf16(A[mt][kk], b[nt], acc[mt][nt], 0, 0, 0);
        }
      }
      __syncthreads();
      buf ^= 1;
    }
    // ---- interval (t, sl=1): ksg 7..12 ----
    {
      if (t < T_TYPES - 1)
        stage<SLAB0_REC>((const char*)g_Wt + (size_t)(t + 1) * T_B, ldsB[buf ^ 1], tid);
      __builtin_amdgcn_sched_barrier(0);
      const char* B = (const char*)ldsB[buf];
#pragma unroll
      for (int kk = 0; kk < 6; ++kk) {
        s16x8 b[NT];
#pragma unroll
        for (int nt = 0; nt < NT; ++nt)
          b[nt] = *(const s16x8*)(B + (kk * 7 + nt) * REC_B + lane * 16);
#pragma unroll
        for (int nt = 0; nt < NT; ++nt) {
#pragma unroll
          for (int mt = 0; mt < 4; ++mt)
            acc[mt][nt] = __builtin_amdgcn_mfma_f32_16x16x32_bf16(A[mt][kk + 7], b[nt], acc[mt][nt], 0, 0, 0);
        }
      }

      // epilogue for t: bias+relu+outW dot, 16-lane reduce, masked running max.
      // regs + stable LDS only; overlaps the in-flight next-t stage.
      {
        float bj[NT], wj[NT];
#pragma unroll
        for (int nt = 0; nt < NT; ++nt) {
          bj[nt] = ldsBias[t * NPAD + nt * 16 + c];
          wj[nt] = ldsOutw[t * NPAD + nt * 16 + c];
        }
        const float ob = ldsOutb[t];
#pragma unroll
        for (int mt = 0; mt < 4; ++mt) {
#pragma unroll
          for (int r = 0; r < 4; ++r) {
            float v = 0.f;
#pragma unroll
            for (int nt = 0; nt < NT; ++nt)
              v += fmaxf(acc[mt][nt][r] + bj[nt], 0.f) * wj[nt];
            v += __shfl_xor(v, 1);
            v += __shfl_xor(v, 2);
            v += __shfl_xor(v, 4);
            v += __shfl_xor(v, 8);
            const float pred = v + ob;
            const int row = w * 64 + mt * 16 + g * 4 + r;   // C/D: row=(lane>>4)*4+reg, col=lane&15
            if (ldsMask[row * T_TYPES + t] != 0)
              runmax[mt][r] = fmaxf(runmax[mt][r], pred);
          }
#pragma unroll
          for (int nt = 0; nt < NT; ++nt) acc[mt][nt] = ZERO4;
        }
      }
      __syncthreads();
      buf ^= 1;
    }
  }

  if (c == 0) {
#pragma unroll
    for (int mt = 0; mt < 4; ++mt)
#pragma unroll
      for (int r = 0; r < 4; ++r) {
        const int row = w * 64 + mt * 16 + g * 4 + r;
        const float v = runmax[mt][r];
        out[P0 + row] = (v > -1e29f) ? v : 0.0f;   // where(any_valid, best, 0)
      }
  }
}

extern "C" void kernel_launch(void* const* d_in, const int* in_sizes, int n_in,
                              void* d_out, int out_size, void* d_ws, size_t ws_size,
                              hipStream_t stream) {
  const float* h    = (const float*)d_in[0];
  const float* srcW = (const float*)d_in[1];
  const float* srcB = (const float*)d_in[2];
  const float* dstW = (const float*)d_in[3];
  const float* dstB = (const float*)d_in[4];
  const float* outW = (const float*)d_in[5];
  const float* outB = (const float*)d_in[6];
  const int*   poss = (const int*)d_in[7];
  float* out = (float*)d_out;

  prep_weights<<<(WT_ELEMS + 255) / 256, 256, 0, stream>>>(srcW, dstW);

  const int nblocks = (2 * E_NODES) / P_TILE;   // 512
  fused_pred<<<nblocks, THREADS, 0, stream>>>(h, srcB, dstB, outW, outB, poss, out);
}

// Round 10
// 326.828 us; speedup vs baseline: 1.2867x; 1.2804x over previous
//
#include <hip/hip_runtime.h>
#include <stdint.h>

// HeteroSTHN edge-predictor, fused bf16-MFMA.
// R6 post-mortem: row-major LDS B = 8-way bank conflict (2.94x port amplifier) -> 164us.
// R8 post-mortem: B direct global->VGPR = latency-bound, 15% MfmaUtil -> 262us.
// R9 post-mortem: 64 rows/wave spilled (VGPR 256 cap, 39MB scratch writes) -> 292us.
// This version:
//  * nt-OUTER accumulation: for nt { for ksg { acc[mt] += A[mt][ksg]*b } ; v[mt] +=
//    relu(acc[mt]+bias)*outw ; } -- acc is [2][1] not [2][7] (56->8 regs), epilogue
//    folds into the nt loop. 32 rows/wave, ~160 VGPR, no spill.
//  * B in LDS, FRAGMENT-MAJOR records: 1024 B per (t,nt,ksg) = one wave's exact MFMA
//    B-fragment; ds_read_b128 at rec*1024+lane*16 is a contiguous wave read ->
//    conflict-free by construction; global_load_lds staging is a pure linear copy.
//  * Slabs = nt-pairs (26 recs, 26.6 KB), double-buffered (LDS 64.5 KB -> 2 blocks/CU),
//    issue-early stage + one __syncthreads per interval (race-free R6 sync structure).

typedef float f32x4 __attribute__((ext_vector_type(4)));
typedef short s16x8 __attribute__((ext_vector_type(8)));

static constexpr int E_NODES = 65536;
static constexpr int D_DIM   = 200;
static constexpr int H_DIM   = 100;
static constexpr int T_TYPES = 8;
static constexpr int NPAD    = 112;   // padded H (7 x 16)
static constexpr int NT      = 7;
static constexpr int KS      = 13;    // K sub-slabs of 32 (merged K: src<200, dst 200..399, pad 416)
static constexpr int P_TILE  = 128;
static constexpr int THREADS = 256;   // 4 waves x 32 rows
static constexpr int REC_B   = 1024;  // bytes per (t,nt,ksg) fragment record
static constexpr int WT_ELEMS = T_TYPES * NT * KS * 512;  // 372736 bf16 = 728 KB
static constexpr int N_GROUPS = 32;                        // 8t x 4 nt-groups {0,1}{2,3}{4,5}{6}
static constexpr int SLAB_MAX_REC = 26;                    // nt-pair slab: 26 recs = 26624 B

__device__ unsigned short g_Wt[WT_ELEMS];   // fragment-major bf16 B image

__device__ __forceinline__ unsigned short f2bf(float f) {
  unsigned int u = __float_as_uint(f);
  u += 0x7FFFu + ((u >> 16) & 1u);   // round-to-nearest-even
  return (unsigned short)(u >> 16);
}

__global__ void prep_weights(const float* __restrict__ srcW, const float* __restrict__ dstW) {
  int idx = blockIdx.x * blockDim.x + threadIdx.x;
  if (idx >= WT_ELEMS) return;
  // element = rec*512 + lane*8 + e ; rec = (t*7 + nt)*13 + ksg   (nt-major for slab contiguity)
  int e   = idx & 7;
  int l   = (idx >> 3) & 63;
  int rec = idx >> 9;
  int ksg = rec % 13;
  int r2  = rec / 13;
  int nt  = r2 % 7;
  int t   = r2 / 7;
  int j   = nt * 16 + (l & 15);             // B col (H dim)
  int k   = ksg * 32 + ((l >> 4) << 3) + e; // merged K
  float v = 0.0f;
  if (j < H_DIM) {
    if (k < D_DIM)          v = srcW[(t * D_DIM + k) * H_DIM + j];
    else if (k < 2 * D_DIM) v = dstW[(t * D_DIM + (k - D_DIM)) * H_DIM + j];
  }
  g_Wt[idx] = f2bf(v);
}

// linear DMA copy of nrec 1024B records into LDS
__device__ __forceinline__ void stage(int rec0, int nrec, unsigned short* dst, int tid) {
  const char* src = (const char*)g_Wt + (size_t)rec0 * REC_B;
  char* d = (char*)dst;
  const int xf = nrec * 64;   // 16B transfers
#pragma unroll
  for (int i = 0; i < 7; ++i) {   // covers up to 1792 xfers (26 recs = 1664)
    const int idx = i * THREADS + tid;
    if (idx < xf) {
      __builtin_amdgcn_global_load_lds(
          (const __attribute__((address_space(1))) void*)(src + idx * 16),
          (__attribute__((address_space(3))) void*)(d + idx * 16),
          16, 0, 0);
    }
  }
}

__global__ __launch_bounds__(THREADS, 2)
void fused_pred(const float* __restrict__ h,
                const float* __restrict__ srcB, const float* __restrict__ dstB,
                const float* __restrict__ outW, const float* __restrict__ outB,
                const int* __restrict__ poss, float* __restrict__ out) {
  __shared__ __align__(16) unsigned short ldsB[2][SLAB_MAX_REC * 512];  // 2 x 26624 B
  __shared__ __align__(16) int ldsMask[P_TILE * T_TYPES];               // 4 KB
  __shared__ float ldsBias[T_TYPES * NPAD];                             // 3.5 KB
  __shared__ float ldsOutw[T_TYPES * NPAD];                             // 3.5 KB
  __shared__ float ldsOutb[T_TYPES];

  const int tid  = threadIdx.x;
  const int lane = tid & 63;
  const int w    = tid >> 6;       // wave 0..3, owns rows [32w, 32w+32)
  const int c    = lane & 15;
  const int g    = lane >> 4;

  // XCD-paired remap: pos/neg tiles over the same src rows adjacent per-XCD.
  const int l     = ((int)blockIdx.x & 7) * 128 + ((int)blockIdx.x >> 3);
  const int which = l & 1;
  const int grp   = l >> 1;
  const int P0    = which * E_NODES + grp * P_TILE;

  // first slab (t0, nt{0,1}) in flight under the whole prologue
  stage(0, SLAB_MAX_REC, ldsB[0], tid);
  __builtin_amdgcn_sched_barrier(0);

  // constants + mask -> LDS
#pragma unroll
  for (int i = 0; i < 4; ++i) {
    int idx = i * THREADS + tid;
    if (idx < T_TYPES * NPAD) {
      int t = idx / NPAD, j = idx - t * NPAD;
      float bb = 0.f, ww = 0.f;
      if (j < H_DIM) {
        bb = srcB[t * H_DIM + j] + dstB[t * H_DIM + j];
        ww = outW[t * H_DIM + j];
      }
      ldsBias[idx] = bb;
      ldsOutw[idx] = ww;
    }
  }
  if (tid < T_TYPES) ldsOutb[tid] = outB[tid];
  ((int4*)ldsMask)[tid] = ((const int4*)(poss + (size_t)P0 * T_TYPES))[tid];  // 256 int4 = 128x8

  // A fragments in registers: A[mt][ks], merged K, k = ks*32 + g*8 + e; 32 rows/wave
  s16x8 A[2][KS];
#pragma unroll
  for (int mt = 0; mt < 2; ++mt) {
    const int row = w * 32 + mt * 16 + c;
    const int p   = P0 + row;
    const float* sp = h + (size_t)(p & (E_NODES - 1)) * D_DIM;
    const float* dp = h + ((size_t)E_NODES + (size_t)p) * D_DIM;
#pragma unroll
    for (int ks = 0; ks < KS; ++ks) {
      const int k0 = ks * 32 + g * 8;
      s16x8 a = {};
      if (k0 < 2 * D_DIM) {                 // only ks=12, g>=2 is pad
        const float* base = (k0 < D_DIM) ? (sp + k0) : (dp + (k0 - D_DIM));
        float4 f0 = *(const float4*)(base);
        float4 f1 = *(const float4*)(base + 4);
        a[0] = (short)f2bf(f0.x); a[1] = (short)f2bf(f0.y);
        a[2] = (short)f2bf(f0.z); a[3] = (short)f2bf(f0.w);
        a[4] = (short)f2bf(f1.x); a[5] = (short)f2bf(f1.y);
        a[6] = (short)f2bf(f1.z); a[7] = (short)f2bf(f1.w);
      }
      A[mt][ks] = a;
    }
  }

  const f32x4 ZERO4 = {0.f, 0.f, 0.f, 0.f};
  f32x4 v0 = ZERO4, v1 = ZERO4;        // per-t running sum_j relu(.)*w_j  (mt=0,1)
  float runmax[2][4];
#pragma unroll
  for (int mt = 0; mt < 2; ++mt)
#pragma unroll
    for (int r = 0; r < 4; ++r) runmax[mt][r] = -1e30f;

  __syncthreads();   // slab 0 staged, constants/mask visible

  int buf = 0;
  for (int t = 0; t < T_TYPES; ++t) {
#pragma unroll
    for (int ng = 0; ng < 4; ++ng) {
      const int gidx = t * 4 + ng;
      // issue next slab first: latency hides under this interval's compute
      if (gidx + 1 < N_GROUPS) {
        const int t1  = (gidx + 1) >> 2;
        const int ng1 = (gidx + 1) & 3;
        stage((t1 * 7 + ng1 * 2) * 13, (ng1 < 3) ? 26 : 13, ldsB[buf ^ 1], tid);
      }
      __builtin_amdgcn_sched_barrier(0);

      const char* B = (const char*)ldsB[buf] + lane * 16;
      const int NL = (ng < 3) ? 2 : 1;
#pragma unroll
      for (int nl = 0; nl < 2; ++nl) {
        if (nl < NL) {
          const int nt = ng * 2 + nl;
          const float bj = ldsBias[t * NPAD + nt * 16 + c];
          const float wj = ldsOutw[t * NPAD + nt * 16 + c];
          f32x4 acc0 = ZERO4, acc1 = ZERO4;
#pragma unroll
          for (int ksg = 0; ksg < KS; ++ksg) {
            s16x8 b = *(const s16x8*)(B + (nl * 13 + ksg) * REC_B);
            acc0 = __builtin_amdgcn_mfma_f32_16x16x32_bf16(A[0][ksg], b, acc0, 0, 0, 0);
            acc1 = __builtin_amdgcn_mfma_f32_16x16x32_bf16(A[1][ksg], b, acc1, 0, 0, 0);
          }
#pragma unroll
          for (int r = 0; r < 4; ++r) {
            v0[r] += fmaxf(acc0[r] + bj, 0.f) * wj;
            v1[r] += fmaxf(acc1[r] + bj, 0.f) * wj;
          }
        }
      }

      if (ng == 3) {
        // finalize t: 16-lane reduce of v over c, +out_b, masked running max
        const float ob = ldsOutb[t];
#pragma unroll
        for (int mt = 0; mt < 2; ++mt) {
#pragma unroll
          for (int r = 0; r < 4; ++r) {
            float vv = (mt == 0) ? v0[r] : v1[r];
            vv += __shfl_xor(vv, 1);
            vv += __shfl_xor(vv, 2);
            vv += __shfl_xor(vv, 4);
            vv += __shfl_xor(vv, 8);
            const float pred = vv + ob;
            const int row = w * 32 + mt * 16 + g * 4 + r;   // C/D: row=(lane>>4)*4+reg, col=lane&15
            if (ldsMask[row * T_TYPES + t] != 0)
              runmax[mt][r] = fmaxf(runmax[mt][r], pred);
          }
        }
        v0 = ZERO4; v1 = ZERO4;
      }

      __syncthreads();   // drains the issued stage; all waves done with ldsB[buf]
      buf ^= 1;
    }
  }

  if (c == 0) {
#pragma unroll
    for (int mt = 0; mt < 2; ++mt)
#pragma unroll
      for (int r = 0; r < 4; ++r) {
        const int row = w * 32 + mt * 16 + g * 4 + r;
        const float v = runmax[mt][r];
        out[P0 + row] = (v > -1e29f) ? v : 0.0f;   // where(any_valid, best, 0)
      }
  }
}

extern "C" void kernel_launch(void* const* d_in, const int* in_sizes, int n_in,
                              void* d_out, int out_size, void* d_ws, size_t ws_size,
                              hipStream_t stream) {
  const float* h    = (const float*)d_in[0];
  const float* srcW = (const float*)d_in[1];
  const float* srcB = (const float*)d_in[2];
  const float* dstW = (const float*)d_in[3];
  const float* dstB = (const float*)d_in[4];
  const float* outW = (const float*)d_in[5];
  const float* outB = (const float*)d_in[6];
  const int*   poss = (const int*)d_in[7];
  float* out = (float*)d_out;

  prep_weights<<<(WT_ELEMS + 255) / 256, 256, 0, stream>>>(srcW, dstW);

  const int nblocks = (2 * E_NODES) / P_TILE;   // 1024
  fused_pred<<<nblocks, THREADS, 0, stream>>>(h, srcB, dstB, outW, outB, poss, out);
}